// Round 1
// baseline (705.477 us; speedup 1.0000x reference)
//
#include <hip/hip_runtime.h>
#include <utility>

// ---------------------------------------------------------------------------
// Compile-time real Clebsch-Gordan table (constexpr port of the reference)
// ---------------------------------------------------------------------------
namespace cg {

constexpr double FACT[13] = {1.,1.,2.,6.,24.,120.,720.,5040.,40320.,362880.,
                             3628800.,39916800.,479001600.};

constexpr double csqrt(double x){
  if (x <= 0.0) return 0.0;
  double g = x > 1.0 ? x : 1.0;
  for (int i = 0; i < 80; i++) g = 0.5*(g + x/g);
  return g;
}

constexpr double cg_complex(int j1,int m1,int j2,int m2,int j3,int m3){
  if (m1+m2 != m3) return 0.0;
  int dj = j1>j2 ? j1-j2 : j2-j1;
  if (j3 < dj || j3 > j1+j2) return 0.0;
  int am1 = m1<0?-m1:m1, am2 = m2<0?-m2:m2, am3 = m3<0?-m3:m3;
  if (am1>j1 || am2>j2 || am3>j3) return 0.0;
  double pref = csqrt((2.0*j3+1.0)*FACT[j3+j1-j2]*FACT[j3-j1+j2]*FACT[j1+j2-j3]
                      /FACT[j1+j2+j3+1]);
  pref *= csqrt(FACT[j3+m3]*FACT[j3-m3]*FACT[j1-m1]*FACT[j1+m1]
               *FACT[j2-m2]*FACT[j2+m2]);
  double s = 0.0;
  for (int k = 0; k <= j1+j2-j3; k++){
    int d1=j1+j2-j3-k, d2=j1-m1-k, d3=j2+m2-k, d4=j3-j2+m1+k, d5=j3-j1-m2+k;
    if (d1<0||d2<0||d3<0||d4<0||d5<0) continue;
    double den = FACT[k]*FACT[d1]*FACT[d2]*FACT[d3]*FACT[d4]*FACT[d5];
    s += ((k&1) ? -1.0 : 1.0)/den;
  }
  return pref*s;
}

struct CD { double re, im; };
struct UMat { CD m[9][9]; };

constexpr UMat makeU(int l){
  UMat U{};
  const double is2 = 1.0/csqrt(2.0);
  for (int mm = -l; mm <= l; mm++){
    int i = mm + l;
    if (mm > 0){
      U.m[i][ mm+l] = CD{((mm&1)?-1.0:1.0)*is2, 0.0};
      U.m[i][-mm+l] = CD{is2, 0.0};
    } else if (mm == 0){
      U.m[i][l] = CD{1.0, 0.0};
    } else {
      int nm = -mm;
      U.m[i][mm+l] = CD{0.0, is2};
      U.m[i][nm+l] = CD{0.0, -((nm&1)?-1.0:1.0)*is2};
    }
  }
  return U;
}

struct CGT { double c[5][5][9]; };

constexpr CGT realCG(int l1,int l2,int l3){
  double base[5][5][9] = {};
  for (int m1 = -l1; m1 <= l1; m1++)
    for (int m2 = -l2; m2 <= l2; m2++){
      int m3 = m1 + m2;
      if (m3 >= -l3 && m3 <= l3)
        base[m1+l1][m2+l2][m3+l3] = cg_complex(l1,m1,l2,m2,l3,m3);
    }
  UMat U1 = makeU(l1), U2 = makeU(l2), U3 = makeU(l3);
  CGT R{};
  const int n1 = 2*l1+1, n2 = 2*l2+1, n3 = 2*l3+1;
  const bool even = ((l1+l2+l3)&1) == 0;
  for (int a = 0; a < n1; a++)
    for (int b = 0; b < n2; b++)
      for (int c = 0; c < n3; c++){
        double sre = 0.0, sim = 0.0;
        for (int x = 0; x < n1; x++){
          CD u1 = U1.m[a][x];
          if (u1.re == 0.0 && u1.im == 0.0) continue;
          u1.im = -u1.im;                        // conj
          for (int y = 0; y < n2; y++){
            CD u2 = U2.m[b][y];
            if (u2.re == 0.0 && u2.im == 0.0) continue;
            u2.im = -u2.im;                      // conj
            CD t12{u1.re*u2.re - u1.im*u2.im, u1.re*u2.im + u1.im*u2.re};
            for (int z = 0; z < n3; z++){
              double bs = base[x][y][z];
              if (bs == 0.0) continue;
              CD u3 = U3.m[c][z];
              if (u3.re == 0.0 && u3.im == 0.0) continue;
              sre += (t12.re*u3.re - t12.im*u3.im)*bs;
              sim += (t12.re*u3.im + t12.im*u3.re)*bs;
            }
          }
        }
        R.c[a][b][c] = even ? sre : sim;
      }
  return R;
}

constexpr int MAXE = 805;
struct Table {
  int n, np;
  int oc[MAXE]; int ia[MAXE]; int ib[MAXE]; int ip[MAXE];
  float v[MAXE];
};

constexpr Table buildTable(){
  Table t{};
  int n = 0, p = 0;
  for (int l1 = 0; l1 <= 2; l1++)
    for (int l2 = 0; l2 <= 2; l2++){
      int lo = l1 > l2 ? l1-l2 : l2-l1;
      int hi = (l1+l2) < 4 ? (l1+l2) : 4;
      for (int l3 = lo; l3 <= hi; l3++){
        int par = (l1+l2+l3)&1;
        CGT C = realCG(l1,l2,l3);
        for (int a = 0; a < 2*l1+1; a++)
          for (int b = 0; b < 2*l2+1; b++)
            for (int c = 0; c < 2*l3+1; c++){
              double v = C.c[a][b][c];
              if (v > 1e-10 || v < -1e-10){
                t.oc[n] = par*25 + l3*l3 + c;
                t.ia[n] = l1*l1 + a;
                t.ib[n] = l2*l2 + b;
                t.ip[n] = p;
                t.v[n]  = (float)v;
                n++;
              }
            }
        p++;
      }
    }
  t.n = n; t.np = p;
  return t;
}

constexpr Table T = buildTable();
static_assert(T.np == 19, "path count mismatch vs reference PATHS");
static_assert(T.n >= 19 && T.n <= MAXE, "nnz sanity");

} // namespace cg

// Fully expanded sparse tensor product: every index is a front-end literal,
// so acc[50]/bx[9]/y2[9]/wv[19] stay in registers.
template <int... Es>
__device__ __forceinline__ void tp_accum(float (&acc)[50], const float (&bx)[9],
                                         const float (&y2)[9], const float (&wv)[19],
                                         std::integer_sequence<int, Es...>){
  ( (acc[cg::T.oc[Es]] +=
       (cg::T.v[Es] * bx[cg::T.ia[Es]]) * (y2[cg::T.ib[Es]] * wv[cg::T.ip[Es]])), ... );
}

// ---------------------------------------------------------------------------
// One 32-lane group per edge (lane == feature), 8 edges per 256-thread block.
// No barriers: every LDS buffer is private to a wave-half, and DS ops from a
// wave are processed in order.
// ---------------------------------------------------------------------------
__global__ __launch_bounds__(256) void btmd_kernel(
    const float* __restrict__ A,  const int* __restrict__ NI,
    const float* __restrict__ D,
    const float* __restrict__ W1, const float* __restrict__ b1,
    const float* __restrict__ GM, const float* __restrict__ BT,
    const float* __restrict__ W2, const float* __restrict__ b2,
    const float* __restrict__ Wb, const float* __restrict__ bb,
    const float* __restrict__ TW, float* __restrict__ out, int nE)
{
  __shared__ alignas(16) float stg[8][288];   // [group][m*32+f]
  __shared__ alignas(16) float radl[8][32];   // [group][k]

  const int lane = threadIdx.x & 31;
  const int grp  = threadIdx.x >> 5;
  const int edge = blockIdx.x * 8 + grp;
  if (edge >= nE) return;

  // ---- gather A[i]+A[j], stage to LDS -------------------------------------
  const int ia_ = NI[2*edge + 0];
  const int ja_ = NI[2*edge + 1];
  const float* Ai = A + (size_t)ia_*288 + lane;
  const float* Aj = A + (size_t)ja_*288 + lane;
#pragma unroll
  for (int m = 0; m < 9; m++)
    stg[grp][m*32 + lane] = Ai[m*32] + Aj[m*32];

  // ---- bond geometry + radial basis (lane == radial index k) --------------
  const float dx = D[3*edge+0], dy = D[3*edge+1], dz = D[3*edge+2];
  const float r    = sqrtf(dx*dx + dy*dy + dz*dz);
  const float rinv = 1.0f / fmaxf(r, 1e-12f);
  const float ux = dx*rinv, uy = dy*rinv, uz = dz*rinv;
  const float S3 = 1.7320508075688772f;
  const float sh1 = uy, sh2 = uz, sh3 = ux;
  const float sh4 = S3*ux*uy, sh5 = S3*uy*uz;
  const float sh6 = 0.5f*(3.0f*uz*uz - 1.0f);
  const float sh7 = S3*ux*uz, sh8 = 0.5f*S3*(ux*ux - uy*uy);
  {
    const float ck  = (5.0f/31.0f)*(float)lane;            // linspace(0,5,32)
    const float dr  = r - ck;
    const float cut = (r < 5.0f)
        ? 0.5f*(__cosf(0.6283185307179586f*r) + 1.0f) : 0.0f;  // pi/CUTOFF
    radl[grp][lane] = __expf(-20.48f*dr*dr) * cut;         // gamma=0.5*(32/5)^2
  }

  // ---- dense1: y0[m] = sum_f yin[m][f]*W1[f][lane] (+b1 at m=0) -----------
  float y0[9];
  {
    float w1c[32];
#pragma unroll
    for (int f = 0; f < 32; f++) w1c[f] = W1[f*32 + lane];
    const float b1v = b1[lane];
#pragma unroll
    for (int m = 0; m < 9; m++){
      float acc = (m == 0) ? b1v : 0.0f;
      const float4* s4 = (const float4*)(&stg[grp][m*32]);
#pragma unroll
      for (int q = 0; q < 8; q++){
        float4 a = s4[q];
        acc += a.x*w1c[4*q+0] + a.y*w1c[4*q+1] + a.z*w1c[4*q+2] + a.w*w1c[4*q+3];
      }
      y0[m] = acc;
    }
  }

  // ---- layernorm stats (butterfly over the 32-lane group) -----------------
  const float s0 = y0[0];
  float sum0 = s0, sumsq0 = s0*s0;
  float ss1 = y0[1]*y0[1] + y0[2]*y0[2] + y0[3]*y0[3];
  float ss2 = y0[4]*y0[4] + y0[5]*y0[5] + y0[6]*y0[6] + y0[7]*y0[7] + y0[8]*y0[8];
#pragma unroll
  for (int off = 16; off >= 1; off >>= 1){
    sum0   += __shfl_xor(sum0,   off, 32);
    sumsq0 += __shfl_xor(sumsq0, off, 32);
    ss1    += __shfl_xor(ss1,    off, 32);
    ss2    += __shfl_xor(ss2,    off, 32);
  }
  const float mu  = sum0*(1.0f/32.0f);
  const float var = sumsq0*(1.0f/32.0f) - mu*mu;
  const float g0 = GM[lane], g1 = GM[32+lane], g2 = GM[64+lane];
  const float shat = (s0 - mu)*rsqrtf(var + 1e-6f)*g0 + BT[lane];
  const float inv1 = rsqrtf(ss1*(1.0f/96.0f)  + 1e-6f)*g1;   // l=1: /(3*32)
  const float inv2 = rsqrtf(ss2*(1.0f/160.0f) + 1e-6f)*g2;   // l=2: /(5*32)

  // ---- mish gate ----------------------------------------------------------
  const float s    = shat;
  const float sp   = fmaxf(s, 0.0f) + log1pf(__expf(-fabsf(s)));  // softplus
  const float e2   = __expf(2.0f*sp);
  const float t    = 1.0f - 2.0f/(e2 + 1.0f);                      // tanh(sp)
  const float sig  = 1.0f/(1.0f + __expf(-s));
  const float dgat = t + s*(1.0f - t*t)*sig;
  const float act  = s*t;

  // ---- stage gated values; dense2 + residual ------------------------------
  stg[grp][lane] = act;
#pragma unroll
  for (int m = 1; m < 4; m++) stg[grp][m*32 + lane] = y0[m]*inv1*dgat;
#pragma unroll
  for (int m = 4; m < 9; m++) stg[grp][m*32 + lane] = y0[m]*inv2*dgat;

  float y2[9];
  {
    float w2c[32];
#pragma unroll
    for (int f = 0; f < 32; f++) w2c[f] = W2[f*32 + lane];
    const float b2v = b2[lane];
#pragma unroll
    for (int m = 0; m < 9; m++){
      float acc = (m == 0) ? b2v : 0.0f;
      const float4* s4 = (const float4*)(&stg[grp][m*32]);
#pragma unroll
      for (int q = 0; q < 8; q++){
        float4 a = s4[q];
        acc += a.x*w2c[4*q+0] + a.y*w2c[4*q+1] + a.z*w2c[4*q+2] + a.w*w2c[4*q+3];
      }
      y2[m] = acc + y0[m];
    }
  }

  // ---- radial projection: g = rad . Wb; bexp[m] = sh[m]*g (+bb at m=0) ----
  float gf;
  {
    float wbc[32];
#pragma unroll
    for (int k = 0; k < 32; k++) wbc[k] = Wb[k*32 + lane];
    float acc = 0.0f;
    const float4* r4 = (const float4*)(&radl[grp][0]);
#pragma unroll
    for (int q = 0; q < 8; q++){
      float4 a = r4[q];
      acc += a.x*wbc[4*q+0] + a.y*wbc[4*q+1] + a.z*wbc[4*q+2] + a.w*wbc[4*q+3];
    }
    gf = acc;
  }
  float bx[9];
  bx[0] = gf + bb[lane];
  bx[1] = sh1*gf; bx[2] = sh2*gf; bx[3] = sh3*gf; bx[4] = sh4*gf;
  bx[5] = sh5*gf; bx[6] = sh6*gf; bx[7] = sh7*gf; bx[8] = sh8*gf;

  // ---- sparse CG tensor product ------------------------------------------
  float wv[19];
#pragma unroll
  for (int p = 0; p < 19; p++) wv[p] = TW[p*32 + lane];
  float acc[50];
#pragma unroll
  for (int c = 0; c < 50; c++) acc[c] = 0.0f;
  tp_accum(acc, bx, y2, wv, std::make_integer_sequence<int, cg::T.n>{});

  // ---- store (E, 2, 25, 32): contiguous 6.4 KB per edge -------------------
  float* op = out + (size_t)edge*1600 + lane;
#pragma unroll
  for (int c = 0; c < 50; c++)
    __builtin_nontemporal_store(acc[c], op + c*32);
}

extern "C" void kernel_launch(void* const* d_in, const int* in_sizes, int n_in,
                              void* d_out, int out_size, void* d_ws, size_t ws_size,
                              hipStream_t stream)
{
  const float* A  = (const float*)d_in[0];   // (10000,1,9,32)
  const int*   NI = (const int*)  d_in[1];   // (100000,2)
  const float* D  = (const float*)d_in[2];   // (100000,3)
  const float* W1 = (const float*)d_in[3];
  const float* b1 = (const float*)d_in[4];
  const float* GM = (const float*)d_in[5];   // ln_gamma (3,32)
  const float* BT = (const float*)d_in[6];   // ln_beta (32)
  const float* W2 = (const float*)d_in[7];
  const float* b2 = (const float*)d_in[8];
  const float* Wb = (const float*)d_in[9];
  const float* bb = (const float*)d_in[10];
  const float* TW = (const float*)d_in[11];  // tp_w (19,32)
  float* out = (float*)d_out;

  const int nE = in_sizes[1] / 2;
  dim3 grid((nE + 7) / 8), block(256);
  btmd_kernel<<<grid, block, 0, stream>>>(A, NI, D, W1, b1, GM, BT, W2, b2,
                                          Wb, bb, TW, out, nE);
}